// Round 5
// baseline (394.053 us; speedup 1.0000x reference)
//
#include <hip/hip_runtime.h>

#define B_ 8
#define NQ_ 2048
#define NK_ 2048
#define D_ 256

typedef __attribute__((ext_vector_type(8))) short bf16x8_t;
typedef __attribute__((ext_vector_type(4))) float f32x4_t;

static __device__ __forceinline__ unsigned short f2bf(float x) {
  unsigned int u = __float_as_uint(x);
  unsigned int r = (u + 0x7FFFu + ((u >> 16) & 1u)) >> 16;
  return (unsigned short)r;
}
static __device__ __forceinline__ float bf2f(unsigned short b) {
  return __uint_as_float(((unsigned int)b) << 16);
}

// ---------------------------------------------------------------------------
// generic f32 -> split bf16 (hi + lo)
// ---------------------------------------------------------------------------
__global__ __launch_bounds__(256) void split_kernel(const float* __restrict__ x,
                                                    unsigned short* __restrict__ xh,
                                                    unsigned short* __restrict__ xl,
                                                    int n) {
  const int i = blockIdx.x * 256 + threadIdx.x;
  if (i < n) {
    const float v = x[i];
    const unsigned short hb = f2bf(v);
    xh[i] = hb;
    xl[i] = f2bf(v - bf2f(hb));
  }
}

// C[i][n] = cos(2*pi*(i*n mod 2048)/2048), i in [0,1152), split bf16
__global__ __launch_bounds__(256) void cos_split_kernel(unsigned short* __restrict__ Ch,
                                                        unsigned short* __restrict__ Cl) {
  const int idx = blockIdx.x * 256 + threadIdx.x;
  const int i = idx >> 11, n = idx & 2047;
  const int m = (i * n) & 2047;
  const float c = cosf((float)m * 0.0030679615757712823f);
  const unsigned short hb = f2bf(c);
  Ch[idx] = hb;
  Cl[idx] = f2bf(c - bf2f(hb));
}

// Qt[b][d][n] = split(query[b][n][d])
__global__ __launch_bounds__(256) void qt_split_kernel(const float* __restrict__ q,
                                                       unsigned short* __restrict__ Qth,
                                                       unsigned short* __restrict__ Qtl) {
  __shared__ float lds[32][33];
  const int t  = threadIdx.x;
  const int n0 = blockIdx.x * 32;
  const int d0 = blockIdx.y * 32;
  const int b  = blockIdx.z;
#pragma unroll
  for (int p = 0; p < 4; ++p) {
    const int idx = t + 256 * p;
    const int dd = idx & 31, nn = idx >> 5;
    lds[nn][dd] = q[((size_t)b * NQ_ + n0 + nn) * D_ + d0 + dd];
  }
  __syncthreads();
#pragma unroll
  for (int p = 0; p < 4; ++p) {
    const int idx = t + 256 * p;
    const int nn = idx & 31, dd = idx >> 5;
    const float v = lds[nn][dd];
    const unsigned short hb = f2bf(v);
    const size_t o = ((size_t)b * D_ + d0 + dd) * NQ_ + n0 + nn;
    Qth[o] = hb;
    Qtl[o] = f2bf(v - bf2f(hb));
  }
}

// Vt[b][d][j] = keyh[b][j][d]
__global__ __launch_bounds__(256) void vt_bf16_kernel(const unsigned short* __restrict__ keyh,
                                                      unsigned short* __restrict__ Vt) {
  __shared__ unsigned short lds[32][40];
  const int t  = threadIdx.x;
  const int j0 = blockIdx.x * 32;
  const int d0 = blockIdx.y * 32;
  const int b  = blockIdx.z;
#pragma unroll
  for (int p = 0; p < 4; ++p) {
    const int idx = t + 256 * p;
    const int dd = idx & 31, jj = idx >> 5;
    lds[jj][dd] = keyh[((size_t)b * NK_ + j0 + jj) * D_ + d0 + dd];
  }
  __syncthreads();
#pragma unroll
  for (int p = 0; p < 4; ++p) {
    const int idx = t + 256 * p;
    const int jj = idx & 31, dd = idx >> 5;
    Vt[((size_t)b * D_ + d0 + dd) * NK_ + j0 + jj] = lds[jj][dd];
  }
}

// ---------------------------------------------------------------------------
// DFT via split-bf16 3-MFMA, K-split=4 (atomicAdd f32 partials). (verified r4)
// ---------------------------------------------------------------------------
__global__ __launch_bounds__(256, 2) void dft_mfma(const unsigned short* __restrict__ Ch,
                                                   const unsigned short* __restrict__ Cl,
                                                   const unsigned short* __restrict__ Qth,
                                                   const unsigned short* __restrict__ Qtl,
                                                   float* __restrict__ qr) {
  __shared__ __align__(16) unsigned short Ah[128][72];
  __shared__ __align__(16) unsigned short Al[128][72];
  __shared__ __align__(16) unsigned short Bh[128][72];
  __shared__ __align__(16) unsigned short Bl[128][72];
  const int t = threadIdx.x;
  const int b = blockIdx.z >> 2, split = blockIdx.z & 3;
  const int i0 = blockIdx.x * 128, d0 = blockIdx.y * 128;
  const int w = t >> 6, lane = t & 63, quad = lane >> 4, l16 = lane & 15;
  const int wq = w & 1, wj = w >> 1;

  f32x4_t acc[4][4];
#pragma unroll
  for (int a = 0; a < 4; ++a)
#pragma unroll
    for (int c = 0; c < 4; ++c) acc[a][c] = (f32x4_t)0.f;

  const size_t abase = (size_t)i0 * 2048;
  const size_t bbase = ((size_t)b * D_ + d0) * 2048;

  for (int c0 = split * 512; c0 < split * 512 + 512; c0 += 64) {
#pragma unroll
    for (int it = 0; it < 4; ++it) {
      const int unit = t + 256 * it;
      const int row = unit >> 3, u = (unit & 7) * 8;
      const size_t go = (size_t)row * 2048 + c0 + u;
      *(uint4*)&Ah[row][u] = *(const uint4*)&Ch[abase + go];
      *(uint4*)&Al[row][u] = *(const uint4*)&Cl[abase + go];
      *(uint4*)&Bh[row][u] = *(const uint4*)&Qth[bbase + go];
      *(uint4*)&Bl[row][u] = *(const uint4*)&Qtl[bbase + go];
    }
    __syncthreads();
#pragma unroll
    for (int ks = 0; ks < 2; ++ks) {
      const int dcol = ks * 32 + quad * 8;
      bf16x8_t ah[4], al[4], bh[4], bl[4];
#pragma unroll
      for (int x = 0; x < 4; ++x) {
        ah[x] = *(const bf16x8_t*)&Ah[wq * 64 + x * 16 + l16][dcol];
        al[x] = *(const bf16x8_t*)&Al[wq * 64 + x * 16 + l16][dcol];
        bh[x] = *(const bf16x8_t*)&Bh[wj * 64 + x * 16 + l16][dcol];
        bl[x] = *(const bf16x8_t*)&Bl[wj * 64 + x * 16 + l16][dcol];
      }
#pragma unroll
      for (int at = 0; at < 4; ++at)
#pragma unroll
        for (int jt = 0; jt < 4; ++jt) {
          acc[at][jt] = __builtin_amdgcn_mfma_f32_16x16x32_bf16(ah[at], bh[jt], acc[at][jt], 0, 0, 0);
          acc[at][jt] = __builtin_amdgcn_mfma_f32_16x16x32_bf16(ah[at], bl[jt], acc[at][jt], 0, 0, 0);
          acc[at][jt] = __builtin_amdgcn_mfma_f32_16x16x32_bf16(al[at], bh[jt], acc[at][jt], 0, 0, 0);
        }
    }
    __syncthreads();
  }
#pragma unroll
  for (int at = 0; at < 4; ++at) {
#pragma unroll
    for (int jt = 0; jt < 4; ++jt) {
      const int d = d0 + wj * 64 + jt * 16 + l16;
#pragma unroll
      for (int r = 0; r < 4; ++r) {
        const int i = i0 + wq * 64 + at * 16 + quad * 4 + r;
        atomicAdd(&qr[((size_t)b * 1152 + i) * D_ + d], acc[at][jt][r]);
      }
    }
  }
}

// qrh/qrl[b][i][d] for all i: src = i<=1087 ? i : 2048-i
__global__ __launch_bounds__(256) void qr_finalize_kernel(const float* __restrict__ qr,
                                                          unsigned short* __restrict__ qrh,
                                                          unsigned short* __restrict__ qrl) {
  const int i = blockIdx.x, b = blockIdx.y, d = threadIdx.x;
  const int src = (i <= 1087) ? i : (2048 - i);
  const float v = qr[((size_t)b * 1152 + src) * D_ + d];
  const unsigned short hb = f2bf(v);
  const size_t o = ((size_t)b * NQ_ + i) * D_ + d;
  qrh[o] = hb;
  qrl[o] = f2bf(v - bf2f(hb));
}

// ---------------------------------------------------------------------------
// y = x @ W.T + bias -- split-bf16 3-MFMA, split epilogue (verified r3/r4)
// ---------------------------------------------------------------------------
__global__ __launch_bounds__(256, 2) void proj_mfma(const unsigned short* __restrict__ xh,
                                                    const unsigned short* __restrict__ xl,
                                                    const unsigned short* __restrict__ Wh,
                                                    const unsigned short* __restrict__ Wl,
                                                    const float* __restrict__ bias,
                                                    unsigned short* __restrict__ yh,
                                                    unsigned short* __restrict__ yl) {
  __shared__ __align__(16) unsigned short Xh[128][72];
  __shared__ __align__(16) unsigned short Xl[128][72];
  __shared__ __align__(16) unsigned short Bh[128][72];
  __shared__ __align__(16) unsigned short Bl[128][72];
  const int t = threadIdx.x;
  const int m0 = blockIdx.x * 128, o0 = blockIdx.y * 128;
  const int w = t >> 6, lane = t & 63, quad = lane >> 4, l16 = lane & 15;
  const int wq = w & 1, wj = w >> 1;

  f32x4_t acc[4][4];
#pragma unroll
  for (int a = 0; a < 4; ++a)
#pragma unroll
    for (int c = 0; c < 4; ++c) acc[a][c] = (f32x4_t)0.f;

  const size_t xbase = (size_t)m0 * D_;
  const size_t wbase = (size_t)o0 * D_;

  for (int c0 = 0; c0 < D_; c0 += 64) {
#pragma unroll
    for (int it = 0; it < 4; ++it) {
      const int unit = t + 256 * it;
      const int row = unit >> 3, u = (unit & 7) * 8;
      const size_t go = (size_t)row * D_ + c0 + u;
      *(uint4*)&Xh[row][u] = *(const uint4*)&xh[xbase + go];
      *(uint4*)&Xl[row][u] = *(const uint4*)&xl[xbase + go];
      *(uint4*)&Bh[row][u] = *(const uint4*)&Wh[wbase + go];
      *(uint4*)&Bl[row][u] = *(const uint4*)&Wl[wbase + go];
    }
    __syncthreads();
#pragma unroll
    for (int ks = 0; ks < 2; ++ks) {
      const int dcol = ks * 32 + quad * 8;
      bf16x8_t ah[4], al[4], bh[4], bl[4];
#pragma unroll
      for (int x = 0; x < 4; ++x) {
        ah[x] = *(const bf16x8_t*)&Xh[wq * 64 + x * 16 + l16][dcol];
        al[x] = *(const bf16x8_t*)&Xl[wq * 64 + x * 16 + l16][dcol];
        bh[x] = *(const bf16x8_t*)&Bh[wj * 64 + x * 16 + l16][dcol];
        bl[x] = *(const bf16x8_t*)&Bl[wj * 64 + x * 16 + l16][dcol];
      }
#pragma unroll
      for (int at = 0; at < 4; ++at)
#pragma unroll
        for (int jt = 0; jt < 4; ++jt) {
          acc[at][jt] = __builtin_amdgcn_mfma_f32_16x16x32_bf16(ah[at], bh[jt], acc[at][jt], 0, 0, 0);
          acc[at][jt] = __builtin_amdgcn_mfma_f32_16x16x32_bf16(ah[at], bl[jt], acc[at][jt], 0, 0, 0);
          acc[at][jt] = __builtin_amdgcn_mfma_f32_16x16x32_bf16(al[at], bh[jt], acc[at][jt], 0, 0, 0);
        }
    }
    __syncthreads();
  }
#pragma unroll
  for (int at = 0; at < 4; ++at) {
#pragma unroll
    for (int jt = 0; jt < 4; ++jt) {
      const int o = o0 + wj * 64 + jt * 16 + l16;
      const float bv = bias[o];
#pragma unroll
      for (int r = 0; r < 4; ++r) {
        const int m = m0 + wq * 64 + at * 16 + quad * 4 + r;
        const float v = acc[at][jt][r] + bv;
        const unsigned short hb = f2bf(v);
        yh[(size_t)m * D_ + o] = hb;
        yl[(size_t)m * D_ + o] = f2bf(v - bf2f(hb));
      }
    }
  }
}

// ---------------------------------------------------------------------------
// Fused flash attention: per block 64 Q-rows (16/wave), KV-range 1024
// (j-split=2), KV-tile 128. Online softmax per wave (rows private to wave).
// Emits unnormalized O (f32) + (m, l) per row per split.
// ---------------------------------------------------------------------------
__global__ __launch_bounds__(256, 2) void flash_mfma(const unsigned short* __restrict__ qh,
                                                     const unsigned short* __restrict__ ql,
                                                     const unsigned short* __restrict__ kh,
                                                     const unsigned short* __restrict__ kl,
                                                     const unsigned short* __restrict__ Vt,
                                                     float* __restrict__ Opart,
                                                     float2* __restrict__ mlpart) {
  __shared__ __align__(16) unsigned char smem[71680];
  unsigned short (*Khs)[72]  = (unsigned short (*)[72])(smem);           // 18432 B
  unsigned short (*Kls)[72]  = (unsigned short (*)[72])(smem + 18432);   // 18432 B
  unsigned short (*Ps)[136]  = (unsigned short (*)[136])(smem + 36864);  // 17408 B
  unsigned short (*Vs)[136]  = (unsigned short (*)[136])(smem + 54272);  // 17408 B
  unsigned short (*Qhs)[264] = (unsigned short (*)[264])(smem);          // 33792 B (start only)
  unsigned short (*Qls)[264] = (unsigned short (*)[264])(smem + 33792);  // 33792 B (start only)

  const int t = threadIdx.x;
  const int w = t >> 6, lane = t & 63, quad = lane >> 4, l16 = lane & 15;
  const int mb = blockIdx.x;          // 0..255
  const int b  = mb >> 5;             // 32 blocks per batch
  const int m0 = mb * 64;             // global Q row (incl. batch)
  const int split = blockIdx.y;       // 0,1

  // --- stage Q tile (64 x 256, hi+lo) and pull fragments into registers ---
  {
    const size_t qbase = (size_t)m0 * D_;
#pragma unroll
    for (int it = 0; it < 8; ++it) {
      const int unit = t + 256 * it;
      const int row = unit >> 5, u = (unit & 31) * 8;
      *(uint4*)&Qhs[row][u] = *(const uint4*)&qh[qbase + (size_t)row * D_ + u];
      *(uint4*)&Qls[row][u] = *(const uint4*)&ql[qbase + (size_t)row * D_ + u];
    }
  }
  __syncthreads();
  bf16x8_t qf_h[8], qf_l[8];
#pragma unroll
  for (int c = 0; c < 8; ++c) {
    qf_h[c] = *(const bf16x8_t*)&Qhs[w * 16 + l16][c * 32 + quad * 8];
    qf_l[c] = *(const bf16x8_t*)&Qls[w * 16 + l16][c * 32 + quad * 8];
  }
  __syncthreads();   // Q region is reused for K/P/V below

  f32x4_t o[16];
#pragma unroll
  for (int df = 0; df < 16; ++df) o[df] = (f32x4_t)0.f;
  float m_run[4], l_run[4];
#pragma unroll
  for (int r = 0; r < 4; ++r) { m_run[r] = -1e30f; l_run[r] = 0.f; }

  for (int it8 = 0; it8 < 8; ++it8) {
    const int j0 = split * 1024 + it8 * 128;

    // --- phase A: S-tile = scale * Q K^T (split-bf16 3-MFMA) ---
    f32x4_t s[8];
#pragma unroll
    for (int jt = 0; jt < 8; ++jt) s[jt] = (f32x4_t)0.f;
#pragma unroll
    for (int dc = 0; dc < 4; ++dc) {
      __syncthreads();
#pragma unroll
      for (int st = 0; st < 4; ++st) {
        const int unit = t + 256 * st;
        const int row = unit >> 3, u = (unit & 7) * 8;
        const size_t go = ((size_t)b * NK_ + j0 + row) * D_ + dc * 64 + u;
        *(uint4*)&Khs[row][u] = *(const uint4*)&kh[go];
        *(uint4*)&Kls[row][u] = *(const uint4*)&kl[go];
      }
      __syncthreads();
#pragma unroll
      for (int ks = 0; ks < 2; ++ks) {
        const int ci = dc * 2 + ks;
#pragma unroll
        for (int jt = 0; jt < 8; ++jt) {
          const bf16x8_t bh = *(const bf16x8_t*)&Khs[jt * 16 + l16][ks * 32 + quad * 8];
          const bf16x8_t bl = *(const bf16x8_t*)&Kls[jt * 16 + l16][ks * 32 + quad * 8];
          s[jt] = __builtin_amdgcn_mfma_f32_16x16x32_bf16(qf_h[ci], bh, s[jt], 0, 0, 0);
          s[jt] = __builtin_amdgcn_mfma_f32_16x16x32_bf16(qf_h[ci], bl, s[jt], 0, 0, 0);
          s[jt] = __builtin_amdgcn_mfma_f32_16x16x32_bf16(qf_l[ci], bh, s[jt], 0, 0, 0);
        }
      }
    }

    // --- phase B: online softmax (rows are (quad, r); cols spread on l16) ---
    float mt[4];
#pragma unroll
    for (int r = 0; r < 4; ++r) mt[r] = -1e30f;
#pragma unroll
    for (int jt = 0; jt < 8; ++jt)
#pragma unroll
      for (int r = 0; r < 4; ++r) {
        s[jt][r] *= 0.0625f;
        mt[r] = fmaxf(mt[r], s[jt][r]);
      }
#pragma unroll
    for (int off = 1; off < 16; off <<= 1)
#pragma unroll
      for (int r = 0; r < 4; ++r) mt[r] = fmaxf(mt[r], __shfl_xor(mt[r], off));
    float al[4], ls[4];
#pragma unroll
    for (int r = 0; r < 4; ++r) {
      const float mn = fmaxf(m_run[r], mt[r]);
      al[r] = __expf(m_run[r] - mn);
      m_run[r] = mn;
      ls[r] = 0.f;
    }
#pragma unroll
    for (int jt = 0; jt < 8; ++jt)
#pragma unroll
      for (int r = 0; r < 4; ++r) {
        const float p = __expf(s[jt][r] - m_run[r]);
        ls[r] += p;
        Ps[w * 16 + quad * 4 + r][jt * 16 + l16] = f2bf(p);  // wave-private rows
      }
#pragma unroll
    for (int off = 1; off < 16; off <<= 1)
#pragma unroll
      for (int r = 0; r < 4; ++r) ls[r] += __shfl_xor(ls[r], off);
#pragma unroll
    for (int r = 0; r < 4; ++r) l_run[r] = l_run[r] * al[r] + ls[r];
#pragma unroll
    for (int df = 0; df < 16; ++df)
#pragma unroll
      for (int r = 0; r < 4; ++r) o[df][r] *= al[r];

    // --- phase C: O += P V (A=P from LDS in A-layout, B=Vt) ---
#pragma unroll
    for (int dc2 = 0; dc2 < 4; ++dc2) {
      __syncthreads();
#pragma unroll
      for (int st = 0; st < 4; ++st) {
        const int unit = t + 256 * st;
        const int row = unit >> 4, u = (unit & 15) * 8;
        *(uint4*)&Vs[row][u] =
            *(const uint4*)&Vt[((size_t)b * D_ + dc2 * 64 + row) * NK_ + j0 + u];
      }
      __syncthreads();
#pragma unroll
      for (int kp = 0; kp < 4; ++kp) {
        const bf16x8_t a = *(const bf16x8_t*)&Ps[w * 16 + l16][kp * 32 + quad * 8];
#pragma unroll
        for (int df = 0; df < 4; ++df) {
          const bf16x8_t bv = *(const bf16x8_t*)&Vs[df * 16 + l16][kp * 32 + quad * 8];
          o[dc2 * 4 + df] =
              __builtin_amdgcn_mfma_f32_16x16x32_bf16(a, bv, o[dc2 * 4 + df], 0, 0, 0);
        }
      }
    }
  }

  // --- epilogue: unnormalized O + (m, l) per row ---
  const size_t obase = ((size_t)split * (B_ * NQ_) + m0 + w * 16) * D_;
#pragma unroll
  for (int df = 0; df < 16; ++df)
#pragma unroll
    for (int r = 0; r < 4; ++r)
      Opart[obase + (size_t)(quad * 4 + r) * D_ + df * 16 + l16] = o[df][r];
  if (l16 == 0) {
#pragma unroll
    for (int r = 0; r < 4; ++r)
      mlpart[split * (B_ * NQ_) + m0 + w * 16 + quad * 4 + r] =
          make_float2(m_run[r], l_run[r]);
  }
}

// ---------------------------------------------------------------------------
// merge 2 KV-splits + normalize: out = (e1*O1 + e2*O2) / (e1*l1 + e2*l2)
// ---------------------------------------------------------------------------
__global__ __launch_bounds__(256) void combine_kernel(const float* __restrict__ Opart,
                                                      const float2* __restrict__ mlpart,
                                                      float* __restrict__ out) {
  const int i = blockIdx.x;        // 0..16383
  const int d = threadIdx.x;
  const float2 s1 = mlpart[i];
  const float2 s2 = mlpart[B_ * NQ_ + i];
  const float M = fmaxf(s1.x, s2.x);
  const float e1 = __expf(s1.x - M), e2 = __expf(s2.x - M);
  const float inv = 1.0f / (e1 * s1.y + e2 * s2.y);
  const float o1 = Opart[(size_t)i * D_ + d];
  const float o2 = Opart[((size_t)B_ * NQ_ + i) * D_ + d];
  out[(size_t)i * D_ + d] = (e1 * o1 + e2 * o2) * inv;
}

extern "C" void kernel_launch(void* const* d_in, const int* in_sizes, int n_in,
                              void* d_out, int out_size, void* d_ws, size_t ws_size,
                              hipStream_t stream) {
  const float* query = (const float*)d_in[0];
  const float* key   = (const float*)d_in[1];
  const float* Wq    = (const float*)d_in[2];
  const float* bq    = (const float*)d_in[3];
  const float* Wk    = (const float*)d_in[4];
  const float* bk    = (const float*)d_in[5];
  float* out = (float*)d_out;

  char* ws = (char*)d_ws;
  const size_t MB = (size_t)1 << 20;
  // persistent:
  unsigned short* qh = (unsigned short*)(ws);            // 8 MB
  unsigned short* ql = (unsigned short*)(ws + 8 * MB);
  unsigned short* kh = (unsigned short*)(ws + 16 * MB);
  unsigned short* kl = (unsigned short*)(ws + 24 * MB);
  unsigned short* Vt = (unsigned short*)(ws + 32 * MB);
  float* Opart  = (float*)(ws + 40 * MB);                // 32 MB
  float2* mlpart = (float2*)(ws + 72 * MB);              // 256 KB
  // transients (dead before flash_mfma):
  unsigned short* Ch   = (unsigned short*)(ws + 73 * MB);   // 4.5 MB
  unsigned short* Cl   = (unsigned short*)(ws + 78 * MB);   // 4.5 MB
  unsigned short* Qth  = (unsigned short*)(ws + 83 * MB);   // 8 MB
  unsigned short* Qtl  = (unsigned short*)(ws + 91 * MB);   // 8 MB
  float*          qr   = (float*)(ws + 99 * MB);            // 9.44 MB
  unsigned short* qrh  = (unsigned short*)(ws + 109 * MB);  // 8 MB
  unsigned short* qrl  = (unsigned short*)(ws + 117 * MB);  // 8 MB
  unsigned short* keyh = (unsigned short*)(ws + 125 * MB);  // 8 MB
  unsigned short* keyl = (unsigned short*)(ws + 133 * MB);  // 8 MB
  unsigned short* Wqh  = (unsigned short*)(ws + 141 * MB);  // 128 KB
  unsigned short* Wql  = (unsigned short*)(ws + 141 * MB + 256 * 1024);
  unsigned short* Wkh  = (unsigned short*)(ws + 141 * MB + 512 * 1024);
  unsigned short* Wkl  = (unsigned short*)(ws + 141 * MB + 768 * 1024);

  dim3 blk(256);
  hipMemsetAsync(qr, 0, (size_t)B_ * 1152 * D_ * sizeof(float), stream);

  split_kernel<<<B_ * NK_ * D_ / 256, blk, 0, stream>>>(key, keyh, keyl, B_ * NK_ * D_);
  split_kernel<<<D_ * D_ / 256, blk, 0, stream>>>(Wq, Wqh, Wql, D_ * D_);
  split_kernel<<<D_ * D_ / 256, blk, 0, stream>>>(Wk, Wkh, Wkl, D_ * D_);
  cos_split_kernel<<<1152 * 2048 / 256, blk, 0, stream>>>(Ch, Cl);
  qt_split_kernel<<<dim3(NQ_ / 32, D_ / 32, B_), blk, 0, stream>>>(query, Qth, Qtl);
  // DFT
  dft_mfma<<<dim3(9, 2, B_ * 4), blk, 0, stream>>>(Ch, Cl, Qth, Qtl, qr);
  qr_finalize_kernel<<<dim3(2048, B_), blk, 0, stream>>>(qr, qrh, qrl);
  // projections
  proj_mfma<<<dim3(B_ * NQ_ / 128, 2), blk, 0, stream>>>(qrh, qrl, Wqh, Wql, bq, qh, ql);
  proj_mfma<<<dim3(B_ * NK_ / 128, 2), blk, 0, stream>>>(keyh, keyl, Wkh, Wkl, bk, kh, kl);
  vt_bf16_kernel<<<dim3(NK_ / 32, D_ / 32, B_), blk, 0, stream>>>(keyh, Vt);
  // fused attention
  flash_mfma<<<dim3(B_ * NQ_ / 64, 2), blk, 0, stream>>>(qh, ql, kh, kl, Vt, Opart, mlpart);
  combine_kernel<<<B_ * NQ_, blk, 0, stream>>>(Opart, mlpart, out);
}